// Round 15
// baseline (131.080 us; speedup 1.0000x reference)
//
#include <hip/hip_runtime.h>

typedef __attribute__((ext_vector_type(2))) float f32x2;
typedef unsigned int uintv2 __attribute__((ext_vector_type(2)));

#define N 256
#define BLK 1024
#define NWAVE 16
#define SCALE 144.2695040888963407f  // log2(e)/0.01
#define TSTRIDE 352                  // rotated tree stride (R12-proven)
#define CTSTRIDE 36                  // transposed-C stride: both R/W conflict-free

template <int CTRL>
__device__ __forceinline__ float dppf(float v) {
  return __int_as_float(__builtin_amdgcn_update_dpp(
      0, __float_as_int(v), CTRL, 0xF, 0xF, true));
}

#if __has_builtin(__builtin_amdgcn_permlane16_swap)
__device__ __forceinline__ float xor16_add(float x) {
  uintv2 r = __builtin_amdgcn_permlane16_swap(__float_as_uint(x),
                                              __float_as_uint(x), false, false);
  return __uint_as_float(r.x) + __uint_as_float(r.y);
}
__device__ __forceinline__ float xor16_max(float x) {
  uintv2 r = __builtin_amdgcn_permlane16_swap(__float_as_uint(x),
                                              __float_as_uint(x), false, false);
  return fmaxf(__uint_as_float(r.x), __uint_as_float(r.y));
}
#else
__device__ __forceinline__ float xor16_add(float x) {
  return x + __int_as_float(__builtin_amdgcn_ds_swizzle(__float_as_int(x), 0x401F));
}
__device__ __forceinline__ float xor16_max(float x) {
  return fmaxf(x, __int_as_float(__builtin_amdgcn_ds_swizzle(__float_as_int(x), 0x401F)));
}
#endif

#if __has_builtin(__builtin_amdgcn_permlane32_swap)
__device__ __forceinline__ float swap32_add(float a) {
  uintv2 r = __builtin_amdgcn_permlane32_swap(__float_as_uint(a),
                                              __float_as_uint(a), false, false);
  return __uint_as_float(r.x) + __uint_as_float(r.y);
}
__device__ __forceinline__ float swap32_max(float a) {
  uintv2 r = __builtin_amdgcn_permlane32_swap(__float_as_uint(a),
                                              __float_as_uint(a), false, false);
  return fmaxf(__uint_as_float(r.x), __uint_as_float(r.y));
}
#else
__device__ __forceinline__ float swap32_add(float a) { return a + __shfl_xor(a, 32); }
__device__ __forceinline__ float swap32_max(float a) { return fmaxf(a, __shfl_xor(a, 32)); }
#endif

__device__ __forceinline__ float rsum32(float v) {
  v += dppf<0x121>(v);
  v += dppf<0x122>(v);
  v += dppf<0x124>(v);
  v += dppf<0x128>(v);
  return xor16_add(v);
}
__device__ __forceinline__ float rmax32(float v) {
  v = fmaxf(v, dppf<0x121>(v));
  v = fmaxf(v, dppf<0x122>(v));
  v = fmaxf(v, dppf<0x124>(v));
  v = fmaxf(v, dppf<0x128>(v));
  return xor16_max(v);
}
__device__ __forceinline__ f32x2 pkmax(f32x2 a, f32x2 b) {
  f32x2 r;
  r.x = fmaxf(a.x, b.x);
  r.y = fmaxf(a.y, b.y);
  return r;
}

// One block = one 256x256 matrix, 16 waves, launch_bounds(1024,2) — the
// proven allocator config (zero spill; forcing 2 blocks/CU spills: R3/R13).
// Thread (rg=tid>>5, cg=tid&31) owns rows rg*8..+7, cols cg*8..+7.
// Dual-scaling Sinkhorn: P = b * R_i * C_j, b STATIC in f32x2 registers,
// input read ONCE, init in-register (R12 trajectory, verified).
// THIS ROUND: main loop restructured for ILP — phase-split (8 independent
// dot-trees; 8 interleaved butterflies; 8 pipelined rcp; 2-chain ps trees)
// to break the per-row ~70-cycle serial chain that held VALUBusy at 44%.
// C layout: transposed stride-36 (write banks 4(i&7)+2w+(i>>3) distinct;
// read lane-stride-1) — both sides conflict-free (fixes R14's 8-way write).
__global__ __launch_bounds__(BLK, 2)
void sinkhorn_kernel(const float* __restrict__ x, float* __restrict__ out) {
  __shared__ float ldsT[NWAVE * TSTRIDE];    // tree partials, rotated layout
  __shared__ float ldsM[N];                  // col max (init)
  __shared__ float ldsCt[7 * CTSTRIDE + 32]; // C transposed: (c&7)*36+(c>>3)

  const int tid = threadIdx.x;
  const int cg = tid & 31;
  const int rg = tid >> 5;
  const int w = tid >> 6;
  const int r0 = rg * 8;
  const int wbase = w * TSTRIDE + cg * 9 + 4 * w;  // this lane's write base
  const long mat = blockIdx.x;

  // ---------- load once: b = x * SCALE (f32x2[8][4]) ----------
  const float4* __restrict__ src4 =
      reinterpret_cast<const float4*>(x + mat * (long)(N * N));
  f32x2 b[8][4];
  #pragma unroll
  for (int r = 0; r < 8; ++r) {
    float4 a = src4[(r0 + r) * 64 + cg * 2];
    float4 bq = src4[(r0 + r) * 64 + cg * 2 + 1];
    b[r][0] = (f32x2){a.x, a.y} * SCALE;
    b[r][1] = (f32x2){a.z, a.w} * SCALE;
    b[r][2] = (f32x2){bq.x, bq.y} * SCALE;
    b[r][3] = (f32x2){bq.z, bq.w} * SCALE;
  }

  // ---------- phase A: u = t - rowlse(t), in-register ----------
  #pragma unroll
  for (int r = 0; r < 8; ++r) {
    f32x2 m2 = pkmax(pkmax(b[r][0], b[r][1]), pkmax(b[r][2], b[r][3]));
    float m = rmax32(fmaxf(m2.x, m2.y));
    float s = 0.f;
    #pragma unroll
    for (int j = 0; j < 4; ++j) {
      s += __builtin_amdgcn_exp2f(b[r][j].x - m);
      s += __builtin_amdgcn_exp2f(b[r][j].y - m);
    }
    s = rsum32(s);
    float L = m + __builtin_amdgcn_logf(s);  // v_log_f32 = log2
    #pragma unroll
    for (int j = 0; j < 4; ++j) b[r][j] -= (f32x2){L, L};
  }

  // ---------- phase B: M_j = colmax(u) via tree ----------
  {
    f32x2 cm[4];
    #pragma unroll
    for (int j = 0; j < 4; ++j) cm[j] = b[0][j];
    #pragma unroll
    for (int r = 1; r < 8; ++r)
      #pragma unroll
      for (int j = 0; j < 4; ++j) cm[j] = pkmax(cm[j], b[r][j]);
    float cmf[8] = {cm[0].x, cm[0].y, cm[1].x, cm[1].y,
                    cm[2].x, cm[2].y, cm[3].x, cm[3].y};
    #pragma unroll
    for (int k = 0; k < 8; ++k) cmf[k] = swap32_max(cmf[k]);
    if (tid & 32) {
      ldsT[wbase + 4] = cmf[4]; ldsT[wbase + 5] = cmf[5];
      ldsT[wbase + 6] = cmf[6]; ldsT[wbase + 7] = cmf[7];
    } else {
      ldsT[wbase + 0] = cmf[0]; ldsT[wbase + 1] = cmf[1];
      ldsT[wbase + 2] = cmf[2]; ldsT[wbase + 3] = cmf[3];
    }
  }
  __syncthreads();
  {
    const int col = tid >> 2, q4 = tid & 3;
    const int slot = (col >> 3) * 9 + (col & 7);
    float M = -3.0e38f;
    #pragma unroll
    for (int k = 0; k < 4; ++k) {
      int row = q4 * 4 + k;
      M = fmaxf(M, ldsT[row * TSTRIDE + slot + 4 * row]);
    }
    M = fmaxf(M, dppf<0xB1>(M));
    M = fmaxf(M, dppf<0x4E>(M));
    if (q4 == 0) ldsM[col] = M;
  }
  __syncthreads();

  // ---------- phase C: b = 2^(u-M-K); G_j = sum_i b*2^{K_i} -> C1 ----------
  {
    const float4* m4 = reinterpret_cast<const float4*>(ldsM);
    float4 mA = m4[cg * 2], mB = m4[cg * 2 + 1];
    f32x2 Mv[4] = {{mA.x, mA.y}, {mA.z, mA.w}, {mB.x, mB.y}, {mB.z, mB.w}};
    f32x2 cs[4];
    cs[0] = cs[1] = cs[2] = cs[3] = (f32x2){0.f, 0.f};
    #pragma unroll
    for (int r = 0; r < 8; ++r) {
      f32x2 v0 = b[r][0] - Mv[0], v1 = b[r][1] - Mv[1];
      f32x2 v2 = b[r][2] - Mv[2], v3 = b[r][3] - Mv[3];
      f32x2 km = pkmax(pkmax(v0, v1), pkmax(v2, v3));
      float K = rmax32(fmaxf(km.x, km.y));  // row max of (u - M), <= 0
      float eK = __builtin_amdgcn_exp2f(K);
      b[r][0].x = __builtin_amdgcn_exp2f(v0.x - K);
      b[r][0].y = __builtin_amdgcn_exp2f(v0.y - K);
      b[r][1].x = __builtin_amdgcn_exp2f(v1.x - K);
      b[r][1].y = __builtin_amdgcn_exp2f(v1.y - K);
      b[r][2].x = __builtin_amdgcn_exp2f(v2.x - K);
      b[r][2].y = __builtin_amdgcn_exp2f(v2.y - K);
      b[r][3].x = __builtin_amdgcn_exp2f(v3.x - K);
      b[r][3].y = __builtin_amdgcn_exp2f(v3.y - K);
      f32x2 eK2 = (f32x2){eK, eK};
      cs[0] += b[r][0] * eK2;
      cs[1] += b[r][1] * eK2;
      cs[2] += b[r][2] * eK2;
      cs[3] += b[r][3] * eK2;
    }
    float csf[8] = {cs[0].x, cs[0].y, cs[1].x, cs[1].y,
                    cs[2].x, cs[2].y, cs[3].x, cs[3].y};
    #pragma unroll
    for (int k = 0; k < 8; ++k) csf[k] = swap32_add(csf[k]);
    if (tid & 32) {
      ldsT[wbase + 4] = csf[4]; ldsT[wbase + 5] = csf[5];
      ldsT[wbase + 6] = csf[6]; ldsT[wbase + 7] = csf[7];
    } else {
      ldsT[wbase + 0] = csf[0]; ldsT[wbase + 1] = csf[1];
      ldsT[wbase + 2] = csf[2]; ldsT[wbase + 3] = csf[3];
    }
  }
  __syncthreads();
  {
    const int col = tid >> 2, q4 = tid & 3;
    const int slot = (col >> 3) * 9 + (col & 7);
    float S = 0.f;
    #pragma unroll
    for (int k = 0; k < 4; ++k) {
      int row = q4 * 4 + k;
      S += ldsT[row * TSTRIDE + slot + 4 * row];
    }
    S += dppf<0xB1>(S);
    S += dppf<0x4E>(S);
    if (q4 == 0)
      ldsCt[(col & 7) * CTSTRIDE + (col >> 3)] =
          __builtin_amdgcn_rcpf(fmaxf(S, 1e-30f));
  }
  __syncthreads();

  // ---------- iterations 2..20 (19x): ILP phase-split ----------
  float Rv[8];
  #pragma unroll 1
  for (int it = 0; it < 20; ++it) {
    f32x2 Cv[4];
    #pragma unroll
    for (int j = 0; j < 4; ++j) {
      Cv[j].x = ldsCt[(2 * j) * CTSTRIDE + cg];      // lane-stride-1
      Cv[j].y = ldsCt[(2 * j + 1) * CTSTRIDE + cg];
    }
    // phase 1: 8 independent dot trees (depth 3)
    float d[8];
    #pragma unroll
    for (int r = 0; r < 8; ++r) {
      f32x2 t0 = b[r][0] * Cv[0] + b[r][1] * Cv[1];
      f32x2 t1 = b[r][2] * Cv[2] + b[r][3] * Cv[3];
      f32x2 t = t0 + t1;
      d[r] = t.x + t.y;
    }
    // phase 2: 8 interleaved butterflies (independent chains)
    #pragma unroll
    for (int r = 0; r < 8; ++r) d[r] += dppf<0x121>(d[r]);
    #pragma unroll
    for (int r = 0; r < 8; ++r) d[r] += dppf<0x122>(d[r]);
    #pragma unroll
    for (int r = 0; r < 8; ++r) d[r] += dppf<0x124>(d[r]);
    #pragma unroll
    for (int r = 0; r < 8; ++r) d[r] += dppf<0x128>(d[r]);
    #pragma unroll
    for (int r = 0; r < 8; ++r) d[r] = xor16_add(d[r]);
    // phase 3: 8 pipelined rcp
    #pragma unroll
    for (int r = 0; r < 8; ++r)
      Rv[r] = __builtin_amdgcn_rcpf(fmaxf(d[r], 1e-30f));
    // phase 4: ps via two alternating accumulator chains per j (depth 4)
    float pf[8];
    #pragma unroll
    for (int j = 0; j < 4; ++j) {
      f32x2 pa = b[0][j] * (f32x2){Rv[0], Rv[0]};
      f32x2 pb = b[1][j] * (f32x2){Rv[1], Rv[1]};
      pa += b[2][j] * (f32x2){Rv[2], Rv[2]};
      pb += b[3][j] * (f32x2){Rv[3], Rv[3]};
      pa += b[4][j] * (f32x2){Rv[4], Rv[4]};
      pb += b[5][j] * (f32x2){Rv[5], Rv[5]};
      pa += b[6][j] * (f32x2){Rv[6], Rv[6]};
      pb += b[7][j] * (f32x2){Rv[7], Rv[7]};
      f32x2 ps = pa + pb;
      pf[2 * j] = ps.x;
      pf[2 * j + 1] = ps.y;
    }
    #pragma unroll
    for (int k = 0; k < 8; ++k) pf[k] = swap32_add(pf[k]);
    if (tid & 32) {
      ldsT[wbase + 4] = pf[4]; ldsT[wbase + 5] = pf[5];
      ldsT[wbase + 6] = pf[6]; ldsT[wbase + 7] = pf[7];
    } else {
      ldsT[wbase + 0] = pf[0]; ldsT[wbase + 1] = pf[1];
      ldsT[wbase + 2] = pf[2]; ldsT[wbase + 3] = pf[3];
    }
    __syncthreads();
    {
      const int col = tid >> 2, q4 = tid & 3;
      const int slot = (col >> 3) * 9 + (col & 7);
      float S = 0.f;
      #pragma unroll
      for (int k = 0; k < 4; ++k) {
        int row = q4 * 4 + k;
        S += ldsT[row * TSTRIDE + slot + 4 * row];
      }
      S += dppf<0xB1>(S);
      S += dppf<0x4E>(S);
      if (q4 == 0)
        ldsCt[(col & 7) * CTSTRIDE + (col >> 3)] =
            __builtin_amdgcn_rcpf(fmaxf(S, 1e-30f));
    }
    __syncthreads();
  }

  // ---------- output: P = b * R_i * C_j (Rv from the 21st iteration) ----------
  f32x2 Cv[4];
  #pragma unroll
  for (int j = 0; j < 4; ++j) {
    Cv[j].x = ldsCt[(2 * j) * CTSTRIDE + cg];
    Cv[j].y = ldsCt[(2 * j + 1) * CTSTRIDE + cg];
  }
  float4* __restrict__ dst4 =
      reinterpret_cast<float4*>(out + mat * (long)(N * N));
  #pragma unroll
  for (int r = 0; r < 8; ++r) {
    f32x2 R2 = (f32x2){Rv[r], Rv[r]};
    f32x2 o0 = b[r][0] * R2 * Cv[0];
    f32x2 o1 = b[r][1] * R2 * Cv[1];
    f32x2 o2 = b[r][2] * R2 * Cv[2];
    f32x2 o3 = b[r][3] * R2 * Cv[3];
    dst4[(r0 + r) * 64 + cg * 2] = make_float4(o0.x, o0.y, o1.x, o1.y);
    dst4[(r0 + r) * 64 + cg * 2 + 1] = make_float4(o2.x, o2.y, o3.x, o3.y);
  }
}

extern "C" void kernel_launch(void* const* d_in, const int* in_sizes, int n_in,
                              void* d_out, int out_size, void* d_ws, size_t ws_size,
                              hipStream_t stream) {
  const float* x = (const float*)d_in[0];
  float* out = (float*)d_out;
  int B = in_sizes[0] / (N * N);
  hipLaunchKernelGGL(sinkhorn_kernel, dim3(B), dim3(BLK), 0, stream, x, out);
}